// Round 1
// baseline (217.952 us; speedup 1.0000x reference)
//
#include <hip/hip_runtime.h>
#include <stdint.h>

#define NNODES 200000
#define BNODES 40000
#define DEG    16
#define DFEAT  128
#define DOUT   256
#define NCLS   128
#define TILE   32   // nodes per block

typedef __attribute__((ext_vector_type(8))) __bf16 bf16x8;
typedef __attribute__((ext_vector_type(4))) float  floatx4;

// round-to-nearest-even fp32 -> bf16 bits
__device__ __forceinline__ uint32_t f2bf(float f) {
  uint32_t x = __float_as_uint(f);
  return ((x + 0x7fffu + ((x >> 16) & 1u)) >> 16) & 0xffffu;
}

__global__ void cvt_weights(const float* __restrict__ W1, const float* __restrict__ W3,
                            uint16_t* __restrict__ w1b, uint16_t* __restrict__ w3b) {
  int i = blockIdx.x * 256 + threadIdx.x;
  if (i < DOUT * 2 * DFEAT) w1b[i] = (uint16_t)f2bf(W1[i]);
  if (i < NCLS * DOUT)      w3b[i] = (uint16_t)f2bf(W3[i]);
}

__global__ __launch_bounds__(256) void sage_fused(
    const int* __restrict__ inputs, const int* __restrict__ nbr,
    const float* __restrict__ feat,
    const uint16_t* __restrict__ w1b, const float* __restrict__ b1,
    const uint16_t* __restrict__ w3b, const float* __restrict__ b3,
    float* __restrict__ out) {
  // padded strides: 264 bf16 = 528 B (16B-aligned rows, 2-way-max LDS bank alias)
  __shared__ __align__(16) uint16_t embL[TILE][264];
  __shared__ __align__(16) uint16_t hL[TILE][264];
  __shared__ __align__(16) float    lgL[TILE][132];

  const int tid  = threadIdx.x;
  const int w    = tid >> 6;       // wave 0..3
  const int lane = tid & 63;
  const int quad = lane >> 4;
  const int l16  = lane & 15;

  // ---------------- Phase 1: gather + segment-mean -> emb (bf16 in LDS) ----
  {
    const int nodeBase = blockIdx.x * TILE + w * 8;
#pragma unroll
    for (int n = 0; n < 8; ++n) {
      const int node = nodeBase + n;
      const int row  = w * 8 + n;
      const int* nb  = nbr + node * DEG;   // wave-uniform -> s_loads
      float sx = 0.f, sy = 0.f;
#pragma unroll
      for (int j = 0; j < DEG; ++j) {
        const float2 v = *(const float2*)(feat + (size_t)nb[j] * DFEAT + lane * 2);
        sx += v.x; sy += v.y;
      }
      const float2 sv = *(const float2*)(feat + (size_t)inputs[node] * DFEAT + lane * 2);
      const uint32_t selfp = f2bf(sv.x) | (f2bf(sv.y) << 16);
      const uint32_t meanp = f2bf(sx * 0.0625f) | (f2bf(sy * 0.0625f) << 16);
      *(uint32_t*)&embL[row][lane * 2]         = selfp;   // dims 2l,2l+1 (self)
      *(uint32_t*)&embL[row][DFEAT + lane * 2] = meanp;   // dims 128+2l (mean)
    }
  }
  __syncthreads();

  const int kq = quad * 8;

  // ---------------- Phase 2: h = relu(emb @ W1^T + b1), bf16 -> LDS --------
  {
    floatx4 acc[2][4];
#pragma unroll
    for (int mt = 0; mt < 2; ++mt)
#pragma unroll
      for (int ot = 0; ot < 4; ++ot) {
        floatx4 z = {0.f, 0.f, 0.f, 0.f};
        acc[mt][ot] = z;
      }
#pragma unroll
    for (int kt = 0; kt < 8; ++kt) {
      const int k0 = kt * 32 + kq;
      const bf16x8 a0 = *(const bf16x8*)&embL[l16][k0];
      const bf16x8 a1 = *(const bf16x8*)&embL[16 + l16][k0];
#pragma unroll
      for (int ot = 0; ot < 4; ++ot) {
        const int o = (w * 4 + ot) * 16 + l16;
        const bf16x8 b = *(const bf16x8*)(w1b + o * 256 + k0);
        acc[0][ot] = __builtin_amdgcn_mfma_f32_16x16x32_bf16(a0, b, acc[0][ot], 0, 0, 0);
        acc[1][ot] = __builtin_amdgcn_mfma_f32_16x16x32_bf16(a1, b, acc[1][ot], 0, 0, 0);
      }
    }
#pragma unroll
    for (int ot = 0; ot < 4; ++ot) {
      const int o = (w * 4 + ot) * 16 + l16;
      const float bias = b1[o];
#pragma unroll
      for (int mt = 0; mt < 2; ++mt)
#pragma unroll
        for (int r = 0; r < 4; ++r) {
          float v = acc[mt][ot][r] + bias;
          v = fmaxf(v, 0.f);
          hL[mt * 16 + quad * 4 + r][o] = (uint16_t)f2bf(v);
        }
    }
  }
  __syncthreads();

  // ---------------- Phase 3: logits = h @ W3^T + b3 -> LDS fp32 ------------
  {
    floatx4 acc2[2][2];
#pragma unroll
    for (int mt = 0; mt < 2; ++mt)
#pragma unroll
      for (int ct = 0; ct < 2; ++ct) {
        floatx4 z = {0.f, 0.f, 0.f, 0.f};
        acc2[mt][ct] = z;
      }
#pragma unroll
    for (int kt = 0; kt < 8; ++kt) {
      const int k0 = kt * 32 + kq;
      const bf16x8 a0 = *(const bf16x8*)&hL[l16][k0];
      const bf16x8 a1 = *(const bf16x8*)&hL[16 + l16][k0];
#pragma unroll
      for (int ct = 0; ct < 2; ++ct) {
        const int c = (w * 2 + ct) * 16 + l16;
        const bf16x8 b = *(const bf16x8*)(w3b + c * 256 + k0);
        acc2[0][ct] = __builtin_amdgcn_mfma_f32_16x16x32_bf16(a0, b, acc2[0][ct], 0, 0, 0);
        acc2[1][ct] = __builtin_amdgcn_mfma_f32_16x16x32_bf16(a1, b, acc2[1][ct], 0, 0, 0);
      }
    }
#pragma unroll
    for (int ct = 0; ct < 2; ++ct) {
      const int c = (w * 2 + ct) * 16 + l16;
      const float bias = b3[c];
#pragma unroll
      for (int mt = 0; mt < 2; ++mt)
#pragma unroll
        for (int r = 0; r < 4; ++r)
          lgL[mt * 16 + quad * 4 + r][c] = acc2[mt][ct][r] + bias;
    }
  }
  __syncthreads();

  // ---------------- Phase 4: row L2-normalize + store ----------------------
  {
    const int nr  = tid >> 3;       // node row 0..31
    const int sub = tid & 7;        // 8 threads per row, 16 cols each
    const float* lrow = &lgL[nr][sub * 16];
    float4 v0 = *(const float4*)(lrow + 0);
    float4 v1 = *(const float4*)(lrow + 4);
    float4 v2 = *(const float4*)(lrow + 8);
    float4 v3 = *(const float4*)(lrow + 12);
    float ss = v0.x * v0.x + v0.y * v0.y + v0.z * v0.z + v0.w * v0.w
             + v1.x * v1.x + v1.y * v1.y + v1.z * v1.z + v1.w * v1.w
             + v2.x * v2.x + v2.y * v2.y + v2.z * v2.z + v2.w * v2.w
             + v3.x * v3.x + v3.y * v3.y + v3.z * v3.z + v3.w * v3.w;
    ss += __shfl_xor(ss, 1);
    ss += __shfl_xor(ss, 2);
    ss += __shfl_xor(ss, 4);
    const float scale = 1.f / fmaxf(sqrtf(ss), 1e-12f);
    v0.x *= scale; v0.y *= scale; v0.z *= scale; v0.w *= scale;
    v1.x *= scale; v1.y *= scale; v1.z *= scale; v1.w *= scale;
    v2.x *= scale; v2.y *= scale; v2.z *= scale; v2.w *= scale;
    v3.x *= scale; v3.y *= scale; v3.z *= scale; v3.w *= scale;
    float* op = out + ((size_t)(blockIdx.x * TILE + nr)) * NCLS + sub * 16;
    *(float4*)(op + 0)  = v0;
    *(float4*)(op + 4)  = v1;
    *(float4*)(op + 8)  = v2;
    *(float4*)(op + 12) = v3;
  }
}

extern "C" void kernel_launch(void* const* d_in, const int* in_sizes, int n_in,
                              void* d_out, int out_size, void* d_ws, size_t ws_size,
                              hipStream_t stream) {
  const int*   inputs = (const int*)d_in[0];
  const int*   nbr    = (const int*)d_in[1];
  // d_in[2] segment_ids: regular repeat(arange(B), 16) -> implicit, unused
  const float* feat   = (const float*)d_in[3];
  const float* W1     = (const float*)d_in[4];
  const float* b1     = (const float*)d_in[5];
  const float* W3     = (const float*)d_in[6];
  const float* b3     = (const float*)d_in[7];

  uint16_t* w1b = (uint16_t*)d_ws;                 // 256*256 bf16
  uint16_t* w3b = w1b + DOUT * 2 * DFEAT;          // 128*256 bf16 (total 192 KiB ws)

  cvt_weights<<<(DOUT * 2 * DFEAT) / 256, 256, 0, stream>>>(W1, W3, w1b, w3b);
  sage_fused<<<BNODES / TILE, 256, 0, stream>>>(inputs, nbr, feat, w1b, b1, w3b, b3,
                                                (float*)d_out);
}